// Round 2
// 130.597 us; speedup vs baseline: 1.0768x; 1.0768x over previous
//
#include <hip/hip_runtime.h>
#include <math.h>

// Problem constants
#define DM   512
#define NH   8
#define HD   64
#define B_   2
#define L_   1024
#define M_   (B_ * L_)   // 2048 rows

typedef __attribute__((ext_vector_type(8))) short  bfrag;   // 8 bf16 (4 VGPRs, 16 B)
typedef __attribute__((ext_vector_type(4))) float  fv4;     // MFMA acc
typedef __attribute__((ext_vector_type(4))) unsigned short usv4;  // 8 B
typedef __attribute__((ext_vector_type(8))) unsigned short usv8;  // 16 B

__device__ __forceinline__ unsigned short f32_bf16_rne(float f) {
    unsigned u = __float_as_uint(f);
    unsigned r = u + 0x7FFF + ((u >> 16) & 1);
    return (unsigned short)(r >> 16);
}
__device__ __forceinline__ float bf16_f32(unsigned short h) {
    return __uint_as_float(((unsigned)h) << 16);
}

// async global->LDS, 16 B per lane. HW semantics: LDS dest = wave-uniform base
// + lane*16 (NOT per-lane scatter) -> LDS tile must be unpadded/lane-contiguous.
__device__ __forceinline__ void stage16(const unsigned short* g, unsigned short* l) {
    __builtin_amdgcn_global_load_lds(
        (const __attribute__((address_space(1))) void*)g,
        (__attribute__((address_space(3))) void*)l,
        16, 0, 0);
}

// ---------------- prep: fp32 -> (hi, lo) bf16 for x and Wq/Wk/Wv; zero z ----------
// (Wo stays fp32: it is consumed by mid_kernel, which folds S into it.)
__global__ __launch_bounds__(256) void prep_kernel(
    const float* __restrict__ x,
    const float* __restrict__ Wq, const float* __restrict__ Wk,
    const float* __restrict__ Wv,
    unsigned short* __restrict__ xh, unsigned short* __restrict__ xl,
    unsigned short* __restrict__ wh, unsigned short* __restrict__ wl,
    float* __restrict__ zred) {
    int bid = blockIdx.x;
    if (bid >= 1792) {   // 1 block: zero the z accumulator (1024 floats, atomicAdd target)
        float4 zv = {0.f, 0.f, 0.f, 0.f};
        *(float4*)(zred + (size_t)threadIdx.x * 4) = zv;
        return;
    }
    const float* src; unsigned short *dh, *dl; size_t off;
    if (bid < 1024) {
        src = x; dh = xh; dl = xl; off = (size_t)bid * 1024;
    } else {
        int wsel = (bid - 1024) >> 8;           // 0..2
        int wb   = (bid - 1024) & 255;
        src = (wsel == 0) ? Wq : (wsel == 1) ? Wk : Wv;
        dh = wh + (size_t)wsel * 262144;
        dl = wl + (size_t)wsel * 262144;
        off = (size_t)wb * 1024;
    }
    size_t i = off + (size_t)threadIdx.x * 4;
    float4 v = *(const float4*)(src + i);
    usv4 h, l;
    h.x = f32_bf16_rne(v.x); l.x = f32_bf16_rne(v.x - bf16_f32(h.x));
    h.y = f32_bf16_rne(v.y); l.y = f32_bf16_rne(v.y - bf16_f32(h.y));
    h.z = f32_bf16_rne(v.z); l.z = f32_bf16_rne(v.z - bf16_f32(h.z));
    h.w = f32_bf16_rne(v.w); l.w = f32_bf16_rne(v.w - bf16_f32(h.w));
    *(usv4*)(dh + i) = h;
    *(usv4*)(dl + i) = l;
}

// ---------------- split-bf16 MFMA GEMM, global_load_lds staging ----------------
// C = A @ W^T + bias (optionally exp()). A: (M,512) hi/lo bf16, W: (512,512) hi/lo.
// C-tile 128x64, 256 threads = 4 waves; wave w covers rows w*32..w*32+31 as
// 2x4 frags of 16x16x32, 3 MFMA passes (Markidis split) per frag.
#define TM 128
#define TN 64
#define TK 32
// LDS row stride = 32 shorts (64 B), UNPADDED: global_load_lds lane-contiguity
// requires it.
#define LDA 32

__device__ __forceinline__ void mfma_gemm_bf16(
    const unsigned short* __restrict__ Ahg, const unsigned short* __restrict__ Alg,
    const unsigned short* __restrict__ Bhg, const unsigned short* __restrict__ Blg,
    const float* __restrict__ bias, float* __restrict__ C, int do_exp) {
    __shared__ __align__(16) unsigned short Ah[TM * LDA];
    __shared__ __align__(16) unsigned short Al[TM * LDA];
    __shared__ __align__(16) unsigned short Bh[TN * LDA];
    __shared__ __align__(16) unsigned short Bl[TN * LDA];

    const int tid  = threadIdx.x;
    const int wave = tid >> 6, lane = tid & 63;
    const int quad = lane >> 4, r16 = lane & 15;
    const int m0 = blockIdx.y * TM, n0 = blockIdx.x * TN;

    const int srow = lane >> 2;
    const int scol = (lane & 3) << 3;

    fv4 acc[2][4] = {};

    for (int k0 = 0; k0 < DM; k0 += TK) {
        {
            const int c1 = wave, c2 = wave + 4;
            size_t ga1 = (size_t)(m0 + c1 * 16 + srow) * DM + k0 + scol;
            size_t ga2 = (size_t)(m0 + c2 * 16 + srow) * DM + k0 + scol;
            stage16(Ahg + ga1, Ah + c1 * 512);
            stage16(Ahg + ga2, Ah + c2 * 512);
            stage16(Alg + ga1, Al + c1 * 512);
            stage16(Alg + ga2, Al + c2 * 512);
            size_t gb = (size_t)(n0 + c1 * 16 + srow) * DM + k0 + scol;
            stage16(Bhg + gb, Bh + c1 * 512);
            stage16(Blg + gb, Bl + c1 * 512);
        }
        __syncthreads();

        bfrag ah[2], al[2], bh[4], bl[4];
#pragma unroll
        for (int i = 0; i < 2; ++i) {
            int off = (wave * 32 + i * 16 + r16) * LDA + quad * 8;
            ah[i] = *(const bfrag*)(Ah + off);
            al[i] = *(const bfrag*)(Al + off);
        }
#pragma unroll
        for (int j = 0; j < 4; ++j) {
            int off = (j * 16 + r16) * LDA + quad * 8;
            bh[j] = *(const bfrag*)(Bh + off);
            bl[j] = *(const bfrag*)(Bl + off);
        }

#pragma unroll
        for (int i = 0; i < 2; ++i)
#pragma unroll
            for (int j = 0; j < 4; ++j) {
                acc[i][j] = __builtin_amdgcn_mfma_f32_16x16x32_bf16(ah[i], bh[j], acc[i][j], 0, 0, 0);
                acc[i][j] = __builtin_amdgcn_mfma_f32_16x16x32_bf16(ah[i], bl[j], acc[i][j], 0, 0, 0);
                acc[i][j] = __builtin_amdgcn_mfma_f32_16x16x32_bf16(al[i], bh[j], acc[i][j], 0, 0, 0);
            }
        __syncthreads();
    }

    // epilogue: D[row = quad*4 + r][col = r16]
#pragma unroll
    for (int j = 0; j < 4; ++j) {
        int n = n0 + j * 16 + r16;
        float bn = bias[n];
#pragma unroll
        for (int i = 0; i < 2; ++i) {
#pragma unroll
            for (int r = 0; r < 4; ++r) {
                int m = m0 + wave * 32 + i * 16 + quad * 4 + r;
                float v = acc[i][j][r] + bn;
                if (do_exp) v = __expf(v);
                C[(size_t)m * DM + n] = v;
            }
        }
    }
}

// QKV: z=0 -> exp(Q), z=1 -> exp(K), z=2 -> V
__global__ __launch_bounds__(256) void gemm_qkv_kernel(
    const unsigned short* __restrict__ xh, const unsigned short* __restrict__ xl,
    const unsigned short* __restrict__ wh, const unsigned short* __restrict__ wl,
    const float* __restrict__ bq, const float* __restrict__ bk, const float* __restrict__ bv,
    float* __restrict__ Qe, float* __restrict__ Ke, float* __restrict__ V) {
    int z = blockIdx.z;
    const float* b = (z == 0) ? bq : (z == 1) ? bk : bv;
    float* C = (z == 0) ? Qe : (z == 1) ? Ke : V;
    mfma_gemm_bf16(xh, xl, wh + (size_t)z * 262144, wl + (size_t)z * 262144,
                   b, C, z < 2);
}

// out = scaled_eq @ W2_b^T; W2 is per-batch (S depends on b): b = m0 >> 10.
__global__ __launch_bounds__(256) void gemm_out_kernel(
    const unsigned short* __restrict__ jh, const unsigned short* __restrict__ jl,
    const unsigned short* __restrict__ w2h, const unsigned short* __restrict__ w2l,
    const float* __restrict__ bo, float* __restrict__ C) {
    int b = blockIdx.y >> 3;   // TM=128: rows 0..1023 -> b=0, 1024..2047 -> b=1
    mfma_gemm_bf16(jh, jl, w2h + (size_t)b * 262144, w2l + (size_t)b * 262144,
                   bo, C, 0);
}

// ---------------- KV stats: partial S[d,e] per (bh, split); z via atomicAdd ------
#define JT 64
__global__ __launch_bounds__(256) void kv_stats_kernel(
    const float* __restrict__ Kbuf, const float* __restrict__ Vbuf,
    float* __restrict__ Spart, float* __restrict__ zred) {
    const int split = blockIdx.x, bh = blockIdx.y;
    const int b = bh >> 3, h = bh & 7;
    const int j0 = split * JT;

    __shared__ __align__(16) float EK[JT][HD + 4];
    __shared__ __align__(16) float VS[JT][HD + 4];

    const int tid = threadIdx.x;
#pragma unroll
    for (int t = 0; t < 4; ++t) {
        int idx = tid + t * 256;
        int r = idx >> 4;
        int c = (idx & 15) << 2;
        size_t row = (size_t)(b * L_ + j0 + r) * DM + h * HD + c;
        *(float4*)&EK[r][c] = *(const float4*)(Kbuf + row);
        *(float4*)&VS[r][c] = *(const float4*)(Vbuf + row);
    }
    __syncthreads();

    const int tx = tid & 15, ty = tid >> 4;
    float acc[4][4] = {{0.f}};
#pragma unroll 8
    for (int jj = 0; jj < JT; ++jj) {
        float4 ek = *(const float4*)&EK[jj][ty * 4];
        float4 vs = *(const float4*)&VS[jj][tx * 4];
        float e[4] = {ek.x, ek.y, ek.z, ek.w};
        float v[4] = {vs.x, vs.y, vs.z, vs.w};
#pragma unroll
        for (int i = 0; i < 4; ++i)
#pragma unroll
            for (int j = 0; j < 4; ++j) acc[i][j] += e[i] * v[j];
    }

    float* sp = Spart + ((size_t)bh * 16 + split) * (HD * HD);
#pragma unroll
    for (int i = 0; i < 4; ++i) {
        float4 o; o.x = acc[i][0]; o.y = acc[i][1]; o.z = acc[i][2]; o.w = acc[i][3];
        *(float4*)(sp + (ty * 4 + i) * HD + tx * 4) = o;
    }
    if (tid < HD) {
        float z = 0.f;
#pragma unroll 8
        for (int jj = 0; jj < JT; ++jj) z += EK[jj][tid];
        atomicAdd(zred + (size_t)bh * HD + tid, z);   // zred[b*512 + h*64 + d]
    }
}

// ---------------- mid: W2 fold + scaled_eq --------------------------------------
// Blocks 0..127:  W2_b[n][h*64+d] = sum_e Wo[n][h*64+e] * S_bh[d][e]  (bf16 hi/lo)
//                 (128 blocks: b x h x n-eighth of 64; S reduced from 16 partials)
// Blocks 128..191: scaled_eq[i][c] = expQ[i][c] / (sum_d expQ[i][h*64+d]*z[b][h*64+d])
//                 written as bf16 hi/lo into jh/jl (A operand of gemm_out).
__global__ __launch_bounds__(256) void mid_kernel(
    const float* __restrict__ Spart, const float* __restrict__ zred,
    const float* __restrict__ Qbuf, const float* __restrict__ Wo,
    unsigned short* __restrict__ w2h, unsigned short* __restrict__ w2l,
    unsigned short* __restrict__ jh, unsigned short* __restrict__ jl) {
    const int tid = threadIdx.x;
    const int bid = blockIdx.x;
    if (bid < 128) {
        __shared__ __align__(16) float Sl[HD][HD + 4];   // pad 68: fp32 float4-aligned, stride%32=4
        __shared__ __align__(16) float Wol[HD][HD + 4];
        const int b = bid >> 6, r = bid & 63;
        const int h = r >> 3, nq = r & 7;
        const int n0 = nq * 64, bh = b * NH + h;
        const float* sp = Spart + (size_t)bh * 16 * (HD * HD);
#pragma unroll
        for (int t4 = 0; t4 < 4; ++t4) {
            int idx4 = tid + t4 * 256;               // 0..1023 (float4 index)
            const float* p0 = sp + (size_t)idx4 * 4;
            float4 s = {0.f, 0.f, 0.f, 0.f};
#pragma unroll
            for (int p = 0; p < 16; ++p) {
                float4 v = *(const float4*)(p0 + (size_t)p * (HD * HD));
                s.x += v.x; s.y += v.y; s.z += v.z; s.w += v.w;
            }
            int d = idx4 >> 4, e4 = (idx4 & 15) << 2;
            *(float4*)&Sl[d][e4] = s;
            *(float4*)&Wol[d][e4] =
                *(const float4*)(Wo + (size_t)(n0 + d) * DM + h * HD + e4);
        }
        __syncthreads();
        // thread -> 4n x 4d register tile; n = n0+nl+j*16 (2-way banks),
        // d = d0+i*16 (Sl reads broadcast within 16-lane group).
        const int nl = tid & 15;
        const int d0 = tid >> 4;
        float acc[4][4] = {};
#pragma unroll
        for (int e4 = 0; e4 < 16; ++e4) {
            float4 w[4], s[4];
#pragma unroll
            for (int j = 0; j < 4; ++j) w[j] = *(const float4*)&Wol[nl + j * 16][e4 * 4];
#pragma unroll
            for (int i = 0; i < 4; ++i) s[i] = *(const float4*)&Sl[d0 + i * 16][e4 * 4];
#pragma unroll
            for (int j = 0; j < 4; ++j)
#pragma unroll
                for (int i = 0; i < 4; ++i)
                    acc[j][i] += w[j].x * s[i].x + w[j].y * s[i].y
                               + w[j].z * s[i].z + w[j].w * s[i].w;
        }
#pragma unroll
        for (int j = 0; j < 4; ++j) {
            int n = n0 + nl + j * 16;
#pragma unroll
            for (int i = 0; i < 4; ++i) {
                int d = d0 + i * 16;
                size_t addr = ((size_t)(b * DM + n)) * DM + h * HD + d;
                float v = acc[j][i];
                unsigned short hh = f32_bf16_rne(v);
                w2h[addr] = hh;
                w2l[addr] = f32_bf16_rne(v - bf16_f32(hh));
            }
        }
    } else {
        const int bid2 = bid - 128;          // 0..63, 32 rows each
        const int w = tid >> 6, lane = tid & 63;
        const int b = bid2 >> 5;             // 32 | 1024 -> batch uniform per block
        const int row0 = bid2 * 32 + w * 8;  // wave handles 8 rows
        // lane covers cols lane*8..lane*8+7, all inside head lane>>3
        const float4 z0 = *(const float4*)(zred + (size_t)b * DM + lane * 8);
        const float4 z1 = *(const float4*)(zred + (size_t)b * DM + lane * 8 + 4);
#pragma unroll
        for (int rr = 0; rr < 8; ++rr) {
            const size_t rowoff = (size_t)(row0 + rr) * DM + lane * 8;
            float4 q0 = *(const float4*)(Qbuf + rowoff);
            float4 q1 = *(const float4*)(Qbuf + rowoff + 4);
            float part = q0.x * z0.x + q0.y * z0.y + q0.z * z0.z + q0.w * z0.w
                       + q1.x * z1.x + q1.y * z1.y + q1.z * z1.z + q1.w * z1.w;
            // reduce within the 8-lane head group
            part += __shfl_xor(part, 1, 64);
            part += __shfl_xor(part, 2, 64);
            part += __shfl_xor(part, 4, 64);
            float inv = 1.0f / part;
            float v[8] = {q0.x * inv, q0.y * inv, q0.z * inv, q0.w * inv,
                          q1.x * inv, q1.y * inv, q1.z * inv, q1.w * inv};
            usv8 hv, lv;
#pragma unroll
            for (int k = 0; k < 8; ++k) {
                unsigned short hh = f32_bf16_rne(v[k]);
                hv[k] = hh;
                lv[k] = f32_bf16_rne(v[k] - bf16_f32(hh));
            }
            *(usv8*)(jh + rowoff) = hv;
            *(usv8*)(jl + rowoff) = lv;
        }
    }
}

// ---------------- launch ----------------
extern "C" void kernel_launch(void* const* d_in, const int* in_sizes, int n_in,
                              void* d_out, int out_size, void* d_ws, size_t ws_size,
                              hipStream_t stream) {
    const float* x  = (const float*)d_in[0];
    const float* Wq = (const float*)d_in[1];
    const float* bq = (const float*)d_in[2];
    const float* Wk = (const float*)d_in[3];
    const float* bk = (const float*)d_in[4];
    const float* Wv = (const float*)d_in[5];
    const float* bv = (const float*)d_in[6];
    const float* Wo = (const float*)d_in[7];
    const float* bo = (const float*)d_in[8];
    float* out = (float*)d_out;

    float* f = (float*)d_ws;
    const size_t NQ = (size_t)M_ * DM;               // 1,048,576
    float* Qe    = f;
    float* Ke    = f + NQ;
    float* V     = f + 2 * NQ;
    float* Spart = f + 3 * NQ;                        // 16*16*4096 = 1M floats
    float* zred  = f + 4 * NQ;                        // 1024 floats (atomic target)
    unsigned short* u = (unsigned short*)(f + 4 * NQ + 1024);
    unsigned short* xh  = u;
    unsigned short* xl  = u + NQ;
    unsigned short* wh  = u + 2 * NQ;                 // 3 x 262144
    unsigned short* wl  = u + 2 * NQ + 786432;
    unsigned short* jh  = u + 2 * NQ + 2 * 786432;
    unsigned short* jl  = jh + NQ;
    unsigned short* w2h = jl + NQ;                    // 2 x 262144
    unsigned short* w2l = w2h + 524288;

    prep_kernel<<<1793, 256, 0, stream>>>(x, Wq, Wk, Wv, xh, xl, wh, wl, zred);

    dim3 gQKV(DM / TN, M_ / TM, 3);   // (8, 16, 3) = 384 blocks
    gemm_qkv_kernel<<<gQKV, 256, 0, stream>>>(xh, xl, wh, wl, bq, bk, bv, Qe, Ke, V);

    kv_stats_kernel<<<dim3(16, 16), 256, 0, stream>>>(Ke, V, Spart, zred);

    mid_kernel<<<192, 256, 0, stream>>>(Spart, zred, Qe, Wo, w2h, w2l, jh, jl);

    dim3 gO(DM / TN, M_ / TM, 1);     // (8, 16) = 128 blocks
    gemm_out_kernel<<<gO, 256, 0, stream>>>(jh, jl, w2h, w2l, bo, out);
}